// Round 14
// baseline (370.365 us; speedup 1.0000x reference)
//
#include <hip/hip_runtime.h>

typedef unsigned short ushort_t;
typedef __attribute__((ext_vector_type(8))) short short8;
typedef __attribute__((ext_vector_type(8))) unsigned short ushort8;
typedef __attribute__((ext_vector_type(4))) float floatx4;

#define KDIM 1024
#define D2   2048
#define NB   1024
#define N2   4096
#define M_TOT 32768

__device__ __forceinline__ ushort_t f2bf(float f){
  unsigned int u = __builtin_bit_cast(unsigned int, f);
  u += 0x7fffu + ((u >> 16) & 1u);           // RNE
  return (ushort_t)(u >> 16);
}
__device__ __forceinline__ float bf2f(ushort_t u){
  return __builtin_bit_cast(float, ((unsigned)u) << 16);
}
__device__ __forceinline__ void gld16(const void* g, void* l){
  __builtin_amdgcn_global_load_lds((__attribute__((address_space(1))) void*)g,
                                   (__attribute__((address_space(3))) void*)l,
                                   16, 0, 0);
}
__device__ __forceinline__ void barrier_raw(){
  asm volatile("" ::: "memory");
  __builtin_amdgcn_s_barrier();
  asm volatile("" ::: "memory");
}
#define WAIT_VM(N)  asm volatile("s_waitcnt vmcnt(" #N ")" ::: "memory")
#define WAIT_LGKM0  asm volatile("s_waitcnt lgkmcnt(0)" ::: "memory")

// ================= prep1: cast_x | trans | bias | wpv1 (all independent) =================
__global__ __launch_bounds__(256) void k_prep1(
    const float* __restrict__ x, ushort_t* __restrict__ xb,
    const float* __restrict__ Wq, const float* __restrict__ Wk,
    ushort_t* __restrict__ WqT, ushort_t* __restrict__ WkT,
    const float* __restrict__ pe, const float* __restrict__ bq,
    const float* __restrict__ bk, float* __restrict__ bias_all,
    const float* __restrict__ Wv, const float* __restrict__ Wfc,
    float* __restrict__ wpv_part){
  __shared__ alignas(16) char smem[16640];
  const int bid = blockIdx.x, t = threadIdx.x;

  if (bid < 16384){
    // ---- cast_x ----
    size_t i = (size_t)bid * 256 + t;
    const float4* s = (const float4*)x;
    float4 a = s[2*i], b = s[2*i+1];
    ushort8 o;
    o[0]=f2bf(a.x); o[1]=f2bf(a.y); o[2]=f2bf(a.z); o[3]=f2bf(a.w);
    o[4]=f2bf(b.x); o[5]=f2bf(b.y); o[6]=f2bf(b.z); o[7]=f2bf(b.w);
    *(ushort8*)(xb + 8*i) = o;
  } else if (bid < 17408){
    // ---- trans: WqT/WkT[j][n] = W[n][j] ----
    int id = bid - 16384;
    int j0 = (id & 15) * 64, n0 = ((id >> 4) & 31) * 64, z = id >> 9;
    const float* in = z ? Wk : Wq;
    ushort_t* out = z ? WkT : WqT;
    float (*tile)[65] = (float(*)[65])smem;
    int rc = t >> 4, cc = (t & 15) * 4;
    #pragma unroll
    for (int p = 0; p < 4; ++p){
      int n = p*16 + rc;
      float4 v = *(const float4*)(in + (size_t)(n0+n)*D2 + j0 + cc);
      tile[n][cc] = v.x; tile[n][cc+1] = v.y; tile[n][cc+2] = v.z; tile[n][cc+3] = v.w;
    }
    __syncthreads();
    #pragma unroll
    for (int p = 0; p < 2; ++p){
      int u = p*256 + t;
      int j = u >> 3, sg = (u & 7)*8;
      ushort8 o;
      #pragma unroll
      for (int e = 0; e < 8; ++e) o[e] = f2bf(tile[sg+e][j]);
      *(ushort8*)(out + (size_t)(j0+j)*D2 + n0 + sg) = o;
    }
  } else if (bid < 17920){
    // ---- bias_all[s][p*2048+n] ----
    int id = bid - 17408;
    int ni = t & 7, s = t >> 3;
    int col = id * 8 + ni;           // 0..4095
    int p = col >> 11, n = col & 2047;
    const float* W  = (p==0) ? Wq : Wk;
    const float* bb = (p==0) ? bq : bk;
    const float4* w4 = (const float4*)(W + (size_t)n*D2 + 1024);
    const float4* p4 = (const float4*)(pe + (size_t)s*1024);
    float acc = 0.f;
    #pragma unroll 4
    for (int j = 0; j < 256; ++j){
      float4 w = w4[j], q = p4[j];
      acc += w.x*q.x + w.y*q.y + w.z*q.z + w.w*q.w;
    }
    bias_all[(size_t)s*N2 + col] = acc + bb[n];
  } else {
    // ---- wpv1 partials ----
    int id = bid - 17920;
    int j = (id & 31)*64 + (t & 63);
    int qg = t >> 6;
    int d0 = (id >> 5) * 128;
    float acc[8] = {};
    for (int d = d0; d < d0+128; ++d){
      float wv = Wv[(size_t)d*D2 + j];
      #pragma unroll
      for (int u = 0; u < 8; ++u)
        acc[u] += wv * Wfc[(size_t)(qg*8+u)*D2 + d];
    }
    #pragma unroll
    for (int u = 0; u < 8; ++u)
      wpv_part[((size_t)(id>>5)*32 + qg*8+u)*D2 + j] = acc[u];
  }
}

// ================= prep2a: wpv2 | mt (both depend only on prep1) =================
__global__ __launch_bounds__(256) void k_prep2a(
    const float* __restrict__ part, float* __restrict__ Wpv, ushort_t* __restrict__ Wpvb,
    const ushort_t* __restrict__ WkT, const ushort_t* __restrict__ WqT,
    float* __restrict__ Mpart){
  __shared__ alignas(16) char smem[32768];
  const int bid = blockIdx.x, t = threadIdx.x;

  if (bid < 256){
    // ---- wpv2: reduce 16 partials -> Wpv fp32 + Wpvb bf16 ----
    int idx = bid*256 + t;   // 0..65535
    int qi = idx >> 11, j = idx & 2047;
    float s = 0.f;
    #pragma unroll
    for (int c = 0; c < 16; ++c)
      s += part[((size_t)c*32 + qi)*D2 + j];
    Wpv[(size_t)qi*D2 + j] = s;
    if (j < 1024) Wpvb[(size_t)qi*KDIM + j] = f2bf(s);
  } else {
    // ---- mt: Mt partials, split-K 8 ----
    int id = bid - 256;
    const int m0 = (id & 7)*128, n0 = ((id >> 3) & 7)*128;
    const size_t kb = (size_t)(id >> 6) * 256;
    ushort_t* sA = (ushort_t*)smem;
    ushort_t* sB = sA + 8192;
    const int w = t >> 6, l = t & 63;
    const int wr = w >> 1, wc = w & 1;
    const int lr = l & 15, lg = l >> 4;
    floatx4 acc[4][4] = {};
    for (int kt = 0; kt < 256; kt += 64){
      #pragma unroll
      for (int j = 0; j < 4; ++j){
        int p = j*256 + t;
        int row = p >> 3, c = (p & 7) ^ (row & 7);
        gld16(WkT + (size_t)(m0+row)*D2 + kb + kt + c*8, &sA[(size_t)(j*256 + w*64)*8]);
        gld16(WqT + (size_t)(n0+row)*D2 + kb + kt + c*8, &sB[(size_t)(j*256 + w*64)*8]);
      }
      __syncthreads();
      #pragma unroll
      for (int ks = 0; ks < 2; ++ks){
        short8 af[4], bfv[4];
        #pragma unroll
        for (int mi = 0; mi < 4; ++mi){
          int ch = (ks*4 + lg) ^ (lr & 7);
          af[mi] = *(const short8*)&sA[(size_t)((wr*64 + mi*16 + lr)*8 + ch)*8];
        }
        #pragma unroll
        for (int ni = 0; ni < 4; ++ni){
          int ch = (ks*4 + lg) ^ (lr & 7);
          bfv[ni] = *(const short8*)&sB[(size_t)((wc*64 + ni*16 + lr)*8 + ch)*8];
        }
        #pragma unroll
        for (int mi = 0; mi < 4; ++mi)
          #pragma unroll
          for (int ni = 0; ni < 4; ++ni)
            acc[mi][ni] = __builtin_amdgcn_mfma_f32_16x16x32_bf16(af[mi], bfv[ni], acc[mi][ni], 0, 0, 0);
      }
      __syncthreads();
    }
    float* o = Mpart + (size_t)(id >> 6)*1024*1024;
    #pragma unroll
    for (int mi = 0; mi < 4; ++mi)
      #pragma unroll
      for (int ni = 0; ni < 4; ++ni)
        #pragma unroll
        for (int r = 0; r < 4; ++r)
          o[(size_t)(m0 + mi*16 + wr*64 + lg*4 + r)*1024 + n0 + wc*64 + ni*16 + lr] = acc[mi][ni][r];
  }
}

// ================= prep2b: mtred | tab =================
__global__ __launch_bounds__(256) void k_prep2b(
    const float* __restrict__ Mp, ushort_t* __restrict__ Mt,
    const ushort_t* __restrict__ WqT, const ushort_t* __restrict__ WkT,
    const float* __restrict__ bias_all, const float* __restrict__ pe,
    const float* __restrict__ Wpv, const float* __restrict__ bv,
    const float* __restrict__ Wfc,
    ushort_t* __restrict__ U, ushort_t* __restrict__ V,
    float* __restrict__ W4, float* __restrict__ biasp){
  const int bid = blockIdx.x, t = threadIdx.x;

  if (bid < 512){
    // ---- mtred: reduce 8 split-K partials -> Mt bf16 ----
    size_t i = ((size_t)bid*256 + t)*8;
    ushort8 o;
    #pragma unroll
    for (int e = 0; e < 8; ++e){
      float s = 0.f;
      #pragma unroll
      for (int c = 0; c < 8; ++c) s += Mp[(size_t)c*1048576 + i + e];
      o[e] = f2bf(s);
    }
    *(ushort8*)(Mt + i) = o;
    return;
  }
  // ---- tab (split-8 per output) ----
  const int tb = bid - 512;       // 0..2111
  const int g = t >> 3;           // output slot (0..31)
  const int k8 = t & 7;           // K-split lane
  if (tb < 2048){
    const bool isU = tb < 1024;
    int oi = (isU ? tb : tb-1024)*32 + g;   // 0..32767
    int s = oi >> 10, j = oi & 1023;
    const ushort_t* wt = (isU ? WqT : WkT) + (size_t)j*D2;
    const float* bias = bias_all + (size_t)s*N2 + (isU ? D2 : 0);
    float acc = 0.f;
    #pragma unroll 4
    for (int it = 0; it < 32; ++it){
      int n = it*64 + k8*8;
      short8 wv = *(const short8*)(wt + n);
      #pragma unroll
      for (int e = 0; e < 8; ++e)
        acc += bf2f((ushort_t)wv[e]) * bias[n+e];
    }
    acc += __shfl_down(acc, 4, 8);
    acc += __shfl_down(acc, 2, 8);
    acc += __shfl_down(acc, 1, 8);
    if (k8 == 0) (isU ? U : V)[(size_t)s*KDIM + j] = f2bf(acc);
  } else if (tb < 2080){
    int oi = (tb-2048)*32 + g;               // 0..1023
    int qi = oi >> 5, ki = oi & 31;
    const float* a = bias_all + (size_t)qi*N2;
    const float* bp = bias_all + (size_t)ki*N2 + D2;
    float acc = 0.f;
    #pragma unroll 4
    for (int it = 0; it < 64; ++it){
      int n = it*32 + k8*4;
      float4 av = *(const float4*)(a + n);
      float4 bv4 = *(const float4*)(bp + n);
      acc += av.x*bv4.x + av.y*bv4.y + av.z*bv4.z + av.w*bv4.w;
    }
    acc += __shfl_down(acc, 4, 8);
    acc += __shfl_down(acc, 2, 8);
    acc += __shfl_down(acc, 1, 8);
    if (k8 == 0) W4[oi] = acc;
  } else {
    int oi = (tb-2080)*32 + g;               // 0..1023
    int s = oi >> 5, qi = oi & 31;
    float acc = 0.f;
    const float* p = pe + (size_t)s*KDIM;
    const float* w = Wpv + (size_t)qi*D2 + 1024;
    #pragma unroll 4
    for (int it = 0; it < 32; ++it){
      int n = it*32 + k8*4;
      float4 av = *(const float4*)(p + n);
      float4 wv = *(const float4*)(w + n);
      acc += av.x*wv.x + av.y*wv.y + av.z*wv.z + av.w*wv.w;
    }
    const float* f = Wfc + (size_t)qi*D2;
    #pragma unroll 4
    for (int it = 0; it < 64; ++it){
      int n = it*32 + k8*4;
      float4 av = *(const float4*)(bv + n);
      float4 wv = *(const float4*)(f + n);
      acc += av.x*wv.x + av.y*wv.y + av.z*wv.z + av.w*wv.w;
    }
    acc += __shfl_down(acc, 4, 8);
    acc += __shfl_down(acc, 2, 8);
    acc += __shfl_down(acc, 1, 8);
    if (k8 == 0) biasp[oi] = acc;
  }
}

// ---------------- 256x256 8-phase GEMM (r7-verified body), templated ----------------
template<int NN, bool HASB>
__global__ __launch_bounds__(512, 1) void k_gemm(const ushort_t* __restrict__ xA,
                                                 const ushort_t* __restrict__ Bm,
                                                 const float* __restrict__ bias_all,
                                                 ushort_t* __restrict__ outm){
  __shared__ alignas(16) ushort_t sA[2][2*128*64];
  __shared__ alignas(16) ushort_t sB[2][2*128*64];

  const int t = threadIdx.x, w = t >> 6, l = t & 63;
  const int wr = w >> 2, wc = w & 3;
  const int lr = l & 15, lg = l >> 4;
  const int m0 = blockIdx.x * 256;
  const int n0 = blockIdx.y * 256;

  const ushort_t* gA = xA + (size_t)m0 * KDIM;
  const ushort_t* gB = Bm + (size_t)n0 * KDIM;

  floatx4 acc[8][4] = {};

  auto STAGE_A = [&](int kt, int d, int h){
    #pragma unroll
    for (int j = 0; j < 2; ++j){
      int p = j*512 + t;
      int wr_ = p >> 9, ridx = (p >> 3) & 63, c = (p & 7) ^ (ridx & 7);
      int R = wr_*128 + h*64 + ridx;
      gld16(gA + (size_t)R*KDIM + kt*64 + c*8, &sA[d][(size_t)h*8192 + (size_t)(j*512 + w*64)*8]);
    }
  };
  auto STAGE_B = [&](int kt, int d, int h){
    #pragma unroll
    for (int j = 0; j < 2; ++j){
      int p = j*512 + t;
      int wc_ = p >> 8, ridx = (p >> 3) & 31, c = (p & 7) ^ (ridx & 7);
      int R = wc_*64 + h*32 + ridx;
      gld16(gB + (size_t)R*KDIM + kt*64 + c*8, &sB[d][(size_t)h*8192 + (size_t)(j*512 + w*64)*8]);
    }
  };

  short8 a[8], b0[4], b1[4];
  auto RDA = [&](int d, int mh){
    #pragma unroll
    for (int mi = 0; mi < 4; ++mi)
      #pragma unroll
      for (int ks = 0; ks < 2; ++ks){
        int ch = (ks*4 + lg) ^ (lr & 7);
        a[mi*2+ks] = *(const short8*)&sA[d][(size_t)mh*8192 + (size_t)(wr*64 + mi*16 + lr)*64 + ch*8];
      }
  };
  auto RDB = [&](int d, int nh, short8* b){
    #pragma unroll
    for (int ni = 0; ni < 2; ++ni)
      #pragma unroll
      for (int ks = 0; ks < 2; ++ks){
        int ch = (ks*4 + lg) ^ (lr & 7);
        b[ni*2+ks] = *(const short8*)&sB[d][(size_t)nh*8192 + (size_t)(wc*32 + ni*16 + lr)*64 + ch*8];
      }
  };
  auto MM = [&](int mh, int nh, const short8* b){
    #pragma unroll
    for (int mi = 0; mi < 4; ++mi)
      #pragma unroll
      for (int ni = 0; ni < 2; ++ni)
        #pragma unroll
        for (int ks = 0; ks < 2; ++ks)
          acc[mh*4+mi][nh*2+ni] = __builtin_amdgcn_mfma_f32_16x16x32_bf16(
              a[mi*2+ks], b[ni*2+ks], acc[mh*4+mi][nh*2+ni], 0, 0, 0);
  };

  #define MIDBAR  do { barrier_raw(); WAIT_LGKM0; __builtin_amdgcn_sched_barrier(0); } while(0)
  #define PRIO_MM(mh, nh, b) do { __builtin_amdgcn_s_setprio(1); MM(mh, nh, b); __builtin_amdgcn_s_setprio(0); } while(0)

  STAGE_A(0,0,0); STAGE_B(0,0,1); STAGE_A(0,0,1); STAGE_B(0,0,0);
  STAGE_A(1,1,0); STAGE_B(1,1,1);
  WAIT_VM(4);
  barrier_raw();

  const int NI = KDIM / 128;
  for (int i = 0; i < NI; ++i){
    const int t1 = 2*i+1, t2 = 2*i+2, t3 = 2*i+3;
    const bool pre = (i < NI-1);

    RDA(0,0); RDB(0,0,b0);
    STAGE_A(t1,1,1); STAGE_B(t1,1,0);
    MIDBAR; PRIO_MM(0,0,b0);
    barrier_raw();
    RDB(0,1,b1);
    MIDBAR; PRIO_MM(0,1,b1);
    barrier_raw();
    RDA(0,1);
    if (pre) STAGE_A(t2,0,0);
    MIDBAR; PRIO_MM(1,1,b1);
    barrier_raw();
    if (pre) STAGE_B(t2,0,1);
    MIDBAR; PRIO_MM(1,0,b0);
    if (pre) { WAIT_VM(4); } else { WAIT_VM(0); }
    barrier_raw();

    RDA(1,0); RDB(1,0,b0);
    if (pre){ STAGE_A(t2,0,1); STAGE_B(t2,0,0); }
    MIDBAR; PRIO_MM(0,0,b0);
    barrier_raw();
    RDB(1,1,b1);
    MIDBAR; PRIO_MM(0,1,b1);
    barrier_raw();
    RDA(1,1);
    if (pre) STAGE_A(t3,1,0);
    MIDBAR; PRIO_MM(1,1,b1);
    barrier_raw();
    if (pre) STAGE_B(t3,1,1);
    MIDBAR; PRIO_MM(1,0,b0);
    if (pre) { WAIT_VM(4); }
    barrier_raw();
  }

  #pragma unroll
  for (int mh = 0; mh < 2; ++mh)
    #pragma unroll
    for (int mi = 0; mi < 4; ++mi)
      #pragma unroll
      for (int nh = 0; nh < 2; ++nh)
        #pragma unroll
        for (int ni = 0; ni < 2; ++ni)
          #pragma unroll
          for (int r = 0; r < 4; ++r){
            int row = m0 + wr*128 + mh*64 + mi*16 + lg*4 + r;
            int col = n0 + wc*64 + nh*32 + ni*16 + lr;
            float v = acc[mh*4+mi][nh*2+ni][r];
            if constexpr (HASB) v += bias_all[(size_t)(row & 31)*NN + col];
            outm[(size_t)row*NN + col] = f2bf(v);
          }
  #undef MIDBAR
  #undef PRIO_MM
}

// ---------------- per-batch tail: 4 small MFMA GEMMs + softmax + weighted sum ----------------
__global__ __launch_bounds__(256) void k_fuse2(
    const ushort_t* __restrict__ xb, const ushort_t* __restrict__ Yb,
    const ushort_t* __restrict__ U, const ushort_t* __restrict__ V,
    const ushort_t* __restrict__ Wpvb, const float* __restrict__ W4,
    const float* __restrict__ biasp, const float* __restrict__ bfc,
    float* __restrict__ out){
  __shared__ float p1[4*1024];
  __shared__ float p3[4*1024];
  __shared__ float pp[4*1024];
  __shared__ float red[4];
  const int b = blockIdx.x;
  const int t = threadIdx.x, w = t >> 6, l = t & 63;
  const int lr = l & 15, lg = l >> 4;
  const int jb = w*256;   // wave's K-slice

  const ushort_t* gx = xb + (size_t)b*32*KDIM;
  const ushort_t* gy = Yb + (size_t)b*32*KDIM;

  short8 xf[2][8], ya[2][8], bo[2][8];
  #pragma unroll
  for (int rf = 0; rf < 2; ++rf)
    #pragma unroll
    for (int ks = 0; ks < 8; ++ks){
      size_t o = (size_t)(rf*16+lr)*KDIM + jb + ks*32 + lg*8;
      xf[rf][ks] = *(const short8*)(gx + o);
      ya[rf][ks] = *(const short8*)(gy + o);
    }
  #pragma unroll
  for (int bf = 0; bf < 2; ++bf)
    #pragma unroll
    for (int ks = 0; ks < 8; ++ks)
      bo[bf][ks] = *(const short8*)(U + (size_t)(bf*16+lr)*KDIM + jb + ks*32 + lg*8);

  floatx4 aL[2][2] = {}, a3[2][2] = {}, aP[2][2] = {};
  #pragma unroll
  for (int rf = 0; rf < 2; ++rf)
    #pragma unroll
    for (int bf = 0; bf < 2; ++bf)
      #pragma unroll
      for (int ks = 0; ks < 8; ++ks){
        aL[rf][bf] = __builtin_amdgcn_mfma_f32_16x16x32_bf16(ya[rf][ks], xf[bf][ks], aL[rf][bf], 0, 0, 0);
        aL[rf][bf] = __builtin_amdgcn_mfma_f32_16x16x32_bf16(xf[rf][ks], bo[bf][ks], aL[rf][bf], 0, 0, 0);
      }
  #pragma unroll
  for (int bf = 0; bf < 2; ++bf)
    #pragma unroll
    for (int ks = 0; ks < 8; ++ks)
      bo[bf][ks] = *(const short8*)(V + (size_t)(bf*16+lr)*KDIM + jb + ks*32 + lg*8);
  #pragma unroll
  for (int rf = 0; rf < 2; ++rf)
    #pragma unroll
    for (int bf = 0; bf < 2; ++bf)
      #pragma unroll
      for (int ks = 0; ks < 8; ++ks)
        a3[rf][bf] = __builtin_amdgcn_mfma_f32_16x16x32_bf16(xf[rf][ks], bo[bf][ks], a3[rf][bf], 0, 0, 0);
  #pragma unroll
  for (int bf = 0; bf < 2; ++bf)
    #pragma unroll
    for (int ks = 0; ks < 8; ++ks)
      bo[bf][ks] = *(const short8*)(Wpvb + (size_t)(bf*16+lr)*KDIM + jb + ks*32 + lg*8);
  #pragma unroll
  for (int rf = 0; rf < 2; ++rf)
    #pragma unroll
    for (int bf = 0; bf < 2; ++bf)
      #pragma unroll
      for (int ks = 0; ks < 8; ++ks)
        aP[rf][bf] = __builtin_amdgcn_mfma_f32_16x16x32_bf16(xf[rf][ks], bo[bf][ks], aP[rf][bf], 0, 0, 0);

  #pragma unroll
  for (int rf = 0; rf < 2; ++rf)
    #pragma unroll
    for (int bf = 0; bf < 2; ++bf)
      #pragma unroll
      for (int r = 0; r < 4; ++r){
        int row = rf*16 + lg*4 + r, col = bf*16 + lr;
        p1[w*1024 + row*32 + col] = aL[rf][bf][r];
        p3[w*1024 + row*32 + col] = a3[rf][bf][r];
        pp[w*1024 + row*32 + col] = aP[rf][bf][r];
      }
  __syncthreads();
  #pragma unroll
  for (int h = 0; h < 4; ++h){
    int idx = h*256 + t;
    float s1 = p1[idx] + p1[1024+idx] + p1[2048+idx] + p1[3072+idx];
    float s3 = p3[idx] + p3[1024+idx] + p3[2048+idx] + p3[3072+idx];
    float sp = pp[idx] + pp[1024+idx] + pp[2048+idx] + pp[3072+idx];
    p1[idx] = s1; p3[idx] = s3; pp[idx] = sp;
  }
  __syncthreads();
  if (t < 32){
    int ki = t;
    float lgv[32];
    float mx = -1e30f;
    #pragma unroll
    for (int qi = 0; qi < 32; ++qi){
      float v = (p1[qi*32+ki] + p3[ki*32+qi] + W4[qi*32+ki]) * 0.022097086912079608f;
      lgv[qi] = v; mx = fmaxf(mx, v);
    }
    float sm = 0.f;
    #pragma unroll
    for (int qi = 0; qi < 32; ++qi){ float e = __expf(lgv[qi]-mx); lgv[qi] = e; sm += e; }
    float inv = 1.f/sm;
    #pragma unroll
    for (int qi = 0; qi < 32; ++qi) p1[qi*32+ki] = lgv[qi]*inv;
  }
  __syncthreads();
  float sum = 0.f;
  #pragma unroll
  for (int h = 0; h < 4; ++h){
    int idx = h*256 + t;
    int qi = idx >> 5, ki = idx & 31;
    sum += p1[qi*32+ki] * (pp[ki*32+qi] + biasp[ki*32+qi]);
  }
  #pragma unroll
  for (int off = 32; off > 0; off >>= 1) sum += __shfl_down(sum, off, 64);
  if (l == 0) red[w] = sum;
  __syncthreads();
  if (t == 0) out[b] = red[0] + red[1] + red[2] + red[3] + bfc[0];
}

// ---------------- host ----------------
extern "C" void kernel_launch(void* const* d_in, const int* in_sizes, int n_in,
                              void* d_out, int out_size, void* d_ws, size_t ws_size,
                              hipStream_t stream) {
  const float* x   = (const float*)d_in[0];
  const float* pe  = (const float*)d_in[1];
  const float* Wq  = (const float*)d_in[2];
  const float* bq  = (const float*)d_in[3];
  const float* Wk  = (const float*)d_in[4];
  const float* bk  = (const float*)d_in[5];
  const float* Wv  = (const float*)d_in[6];
  const float* bv  = (const float*)d_in[7];
  const float* Wfc = (const float*)d_in[8];
  const float* bfc = (const float*)d_in[9];
  float* out = (float*)d_out;
  (void)in_sizes; (void)n_in; (void)out_size; (void)ws_size;

  char* ws = (char*)d_ws;
  size_t off = 0;
  auto alloc = [&](size_t bytes) -> void* {
    void* p = ws + off;
    off += (bytes + 255) & ~(size_t)255;
    return p;
  };
  ushort_t* xb       = (ushort_t*)alloc((size_t)M_TOT * KDIM * 2);   //  64 MiB
  ushort_t* Y        = (ushort_t*)alloc((size_t)M_TOT * KDIM * 2);   //  64 MiB
  ushort_t* WqT      = (ushort_t*)alloc((size_t)KDIM * D2 * 2);      //   4 MiB
  ushort_t* WkT      = (ushort_t*)alloc((size_t)KDIM * D2 * 2);      //   4 MiB
  float*    Mpart    = (float*)   alloc((size_t)8 * KDIM * KDIM * 4);// 32 MiB
  ushort_t* Mt       = (ushort_t*)alloc((size_t)KDIM * KDIM * 2);    //   2 MiB
  float*    wpv_part = (float*)   alloc((size_t)16 * 32 * D2 * 4);   //   4 MiB
  float*    Wpv      = (float*)   alloc((size_t)32 * D2 * 4);        // 256 KiB
  ushort_t* Wpvb     = (ushort_t*)alloc((size_t)32 * KDIM * 2);      //  64 KiB
  float*    bias_all = (float*)   alloc((size_t)32 * N2 * 4);        // 512 KiB
  ushort_t* U        = (ushort_t*)alloc((size_t)32 * KDIM * 2);      //  64 KiB
  ushort_t* V        = (ushort_t*)alloc((size_t)32 * KDIM * 2);      //  64 KiB
  float*    W4       = (float*)   alloc((size_t)32 * 32 * 4);        //   4 KiB
  float*    biasp    = (float*)   alloc((size_t)32 * 32 * 4);        //   4 KiB

  k_prep1 <<<dim3(18432), dim3(256), 0, stream>>>(x, xb, Wq, Wk, WqT, WkT,
                                                  pe, bq, bk, bias_all, Wv, Wfc, wpv_part);
  k_prep2a<<<dim3(768),   dim3(256), 0, stream>>>(wpv_part, Wpv, Wpvb, WkT, WqT, Mpart);
  k_prep2b<<<dim3(2624),  dim3(256), 0, stream>>>(Mpart, Mt, WqT, WkT, bias_all, pe,
                                                  Wpv, bv, Wfc, U, V, W4, biasp);
  k_gemm<1024,false><<<dim3(M_TOT/256, 4), dim3(512), 0, stream>>>(xb, Mt, nullptr, Y);
  k_fuse2 <<<dim3(NB),    dim3(256), 0, stream>>>(xb, Y, U, V, Wpvb, W4, biasp, bfc, out);
}

// Round 15
// 298.808 us; speedup vs baseline: 1.2395x; 1.2395x over previous
//
#include <hip/hip_runtime.h>

typedef unsigned short ushort_t;
typedef __attribute__((ext_vector_type(8))) short short8;
typedef __attribute__((ext_vector_type(8))) unsigned short ushort8;
typedef __attribute__((ext_vector_type(4))) float floatx4;

#define KDIM 1024
#define D2   2048
#define NB   1024
#define N2   4096
#define M_TOT 32768

__device__ __forceinline__ ushort_t f2bf(float f){
  unsigned int u = __builtin_bit_cast(unsigned int, f);
  u += 0x7fffu + ((u >> 16) & 1u);           // RNE
  return (ushort_t)(u >> 16);
}
__device__ __forceinline__ float bf2f(ushort_t u){
  return __builtin_bit_cast(float, ((unsigned)u) << 16);
}
__device__ __forceinline__ void gld16(const void* g, void* l){
  __builtin_amdgcn_global_load_lds((__attribute__((address_space(1))) void*)g,
                                   (__attribute__((address_space(3))) void*)l,
                                   16, 0, 0);
}
__device__ __forceinline__ void barrier_raw(){
  asm volatile("" ::: "memory");
  __builtin_amdgcn_s_barrier();
  asm volatile("" ::: "memory");
}
#define WAIT_VM(N)  asm volatile("s_waitcnt vmcnt(" #N ")" ::: "memory")
#define WAIT_LGKM0  asm volatile("s_waitcnt lgkmcnt(0)" ::: "memory")

// ---------------- prep kernels (r13 green config) ----------------

__global__ void k_cast_x(const float* __restrict__ x, ushort_t* __restrict__ xb){
  size_t i = (size_t)blockIdx.x * 256 + threadIdx.x;
  const float4* s = (const float4*)x;
  float4 a = s[2*i], b = s[2*i+1];
  ushort8 o;
  o[0]=f2bf(a.x); o[1]=f2bf(a.y); o[2]=f2bf(a.z); o[3]=f2bf(a.w);
  o[4]=f2bf(b.x); o[5]=f2bf(b.y); o[6]=f2bf(b.z); o[7]=f2bf(b.w);
  *(ushort8*)(xb + 8*i) = o;
}

// WqT[j][n] = Wq[n][j] (bf16), j<1024, n<2048; z selects Wq/Wk
__global__ void k_trans(const float* __restrict__ Wq, const float* __restrict__ Wk,
                        ushort_t* __restrict__ WqT, ushort_t* __restrict__ WkT){
  __shared__ float tile[64][65];
  const float* in = blockIdx.z ? Wk : Wq;
  ushort_t* out = blockIdx.z ? WkT : WqT;
  int j0 = blockIdx.x * 64;      // 16 blocks
  int n0 = blockIdx.y * 64;      // 32 blocks
  int t = threadIdx.x;
  int rc = t >> 4, cc = (t & 15) * 4;
  #pragma unroll
  for (int p = 0; p < 4; ++p){
    int n = p*16 + rc;
    float4 v = *(const float4*)(in + (size_t)(n0+n)*D2 + j0 + cc);
    tile[n][cc] = v.x; tile[n][cc+1] = v.y; tile[n][cc+2] = v.z; tile[n][cc+3] = v.w;
  }
  __syncthreads();
  #pragma unroll
  for (int p = 0; p < 2; ++p){
    int u = p*256 + t;
    int j = u >> 3, sg = (u & 7)*8;
    ushort8 o;
    #pragma unroll
    for (int e = 0; e < 8; ++e) o[e] = f2bf(tile[sg+e][j]);
    *(ushort8*)(out + (size_t)(j0+j)*D2 + n0 + sg) = o;
  }
}

// bias_all[s][p*2048+n] = b_p[n] + pe[s]·W_p[n][1024:]  (fp32), p in {q,k}
__global__ void k_bias(const float* __restrict__ pe,
                       const float* __restrict__ Wq, const float* __restrict__ bq,
                       const float* __restrict__ Wk, const float* __restrict__ bk,
                       float* __restrict__ bias_all){
  int t = threadIdx.x;
  int ni = t & 7, s = t >> 3;
  int col = blockIdx.x * 8 + ni;           // 0..4095
  int p = col >> 11, n = col & 2047;
  const float* W  = (p==0) ? Wq : Wk;
  const float* bb = (p==0) ? bq : bk;
  const float4* w4 = (const float4*)(W + (size_t)n*D2 + 1024);
  const float4* p4 = (const float4*)(pe + (size_t)s*1024);
  float acc = 0.f;
  #pragma unroll 4
  for (int j = 0; j < 256; ++j){
    float4 w = w4[j], q = p4[j];
    acc += w.x*q.x + w.y*q.y + w.z*q.z + w.w*q.w;
  }
  bias_all[(size_t)s*N2 + col] = acc + bb[n];
}

// Mt partials; split-K: grid (8,8,8), 128^2 tile, K-chunk 256
__global__ __launch_bounds__(256) void k_mt(const ushort_t* __restrict__ WkT,
                                            const ushort_t* __restrict__ WqT,
                                            float* __restrict__ Mpart){
  __shared__ alignas(16) ushort_t sA[128*64], sB[128*64];
  const int m0 = blockIdx.x*128, n0 = blockIdx.y*128;
  const size_t kb = (size_t)blockIdx.z * 256;
  const int t = threadIdx.x, w = t >> 6, l = t & 63;
  const int wr = w >> 1, wc = w & 1;
  const int lr = l & 15, lg = l >> 4;
  floatx4 acc[4][4] = {};
  for (int kt = 0; kt < 256; kt += 64){
    #pragma unroll
    for (int j = 0; j < 4; ++j){
      int p = j*256 + t;
      int row = p >> 3, c = (p & 7) ^ (row & 7);
      gld16(WkT + (size_t)(m0+row)*D2 + kb + kt + c*8, &sA[(size_t)(j*256 + w*64)*8]);
      gld16(WqT + (size_t)(n0+row)*D2 + kb + kt + c*8, &sB[(size_t)(j*256 + w*64)*8]);
    }
    __syncthreads();
    #pragma unroll
    for (int ks = 0; ks < 2; ++ks){
      short8 af[4], bfv[4];
      #pragma unroll
      for (int mi = 0; mi < 4; ++mi){
        int ch = (ks*4 + lg) ^ (lr & 7);
        af[mi] = *(const short8*)&sA[(size_t)((wr*64 + mi*16 + lr)*8 + ch)*8];
      }
      #pragma unroll
      for (int ni = 0; ni < 4; ++ni){
        int ch = (ks*4 + lg) ^ (lr & 7);
        bfv[ni] = *(const short8*)&sB[(size_t)((wc*64 + ni*16 + lr)*8 + ch)*8];
      }
      #pragma unroll
      for (int mi = 0; mi < 4; ++mi)
        #pragma unroll
        for (int ni = 0; ni < 4; ++ni)
          acc[mi][ni] = __builtin_amdgcn_mfma_f32_16x16x32_bf16(af[mi], bfv[ni], acc[mi][ni], 0, 0, 0);
    }
    __syncthreads();
  }
  float* o = Mpart + (size_t)blockIdx.z*1024*1024;
  #pragma unroll
  for (int mi = 0; mi < 4; ++mi)
    #pragma unroll
    for (int ni = 0; ni < 4; ++ni)
      #pragma unroll
      for (int r = 0; r < 4; ++r)
        o[(size_t)(m0 + mi*16 + wr*64 + lg*4 + r)*1024 + n0 + wc*64 + ni*16 + lr] = acc[mi][ni][r];
}

// Wpv partials: part[dt][qi][j] = sum_{d in chunk} Wfc[qi][d] Wv[d][j]
__global__ void k_wpv1(const float* __restrict__ Wv, const float* __restrict__ Wfc,
                       float* __restrict__ part){
  int j = blockIdx.x*64 + (threadIdx.x & 63);
  int qg = threadIdx.x >> 6;
  int d0 = blockIdx.y * 128;
  float acc[8] = {};
  for (int d = d0; d < d0+128; ++d){
    float wv = Wv[(size_t)d*D2 + j];
    #pragma unroll
    for (int u = 0; u < 8; ++u)
      acc[u] += wv * Wfc[(size_t)(qg*8+u)*D2 + d];
  }
  #pragma unroll
  for (int u = 0; u < 8; ++u)
    part[((size_t)blockIdx.y*32 + qg*8+u)*D2 + j] = acc[u];
}

// merged streaming reductions: blocks [0,512): mtred; [512,768): wpv2
__global__ void k_red(const float* __restrict__ Mp, ushort_t* __restrict__ Mt,
                      const float* __restrict__ part, float* __restrict__ Wpv,
                      ushort_t* __restrict__ Wpvb){
  const int bid = blockIdx.x, t = threadIdx.x;
  if (bid < 512){
    size_t i = ((size_t)bid*256 + t)*8;
    ushort8 o;
    #pragma unroll
    for (int e = 0; e < 8; ++e){
      float s = 0.f;
      #pragma unroll
      for (int c = 0; c < 8; ++c) s += Mp[(size_t)c*1048576 + i + e];
      o[e] = f2bf(s);
    }
    *(ushort8*)(Mt + i) = o;
  } else {
    int idx = (bid-512)*256 + t;   // 0..65535
    int qi = idx >> 11, j = idx & 2047;
    float s = 0.f;
    #pragma unroll
    for (int c = 0; c < 16; ++c)
      s += part[((size_t)c*32 + qi)*D2 + j];
    Wpv[(size_t)qi*D2 + j] = s;
    if (j < 1024) Wpvb[(size_t)qi*KDIM + j] = f2bf(s);
  }
}

// split-8-per-output tables kernel (r13 green):
__global__ void k_tab(const ushort_t* __restrict__ WqT, const ushort_t* __restrict__ WkT,
                      const float* __restrict__ bias_all,
                      const float* __restrict__ pe, const float* __restrict__ Wpv,
                      const float* __restrict__ bv, const float* __restrict__ Wfc,
                      ushort_t* __restrict__ U, ushort_t* __restrict__ V,
                      float* __restrict__ W4, float* __restrict__ biasp){
  const int bid = blockIdx.x, t = threadIdx.x;
  const int g = t >> 3;        // output slot within block (0..31)
  const int k8 = t & 7;        // K-split lane
  if (bid < 2048){
    const bool isU = bid < 1024;
    int oi = (isU ? bid : bid-1024)*32 + g;   // 0..32767
    int s = oi >> 10, j = oi & 1023;
    const ushort_t* wt = (isU ? WqT : WkT) + (size_t)j*D2;
    const float* bias = bias_all + (size_t)s*N2 + (isU ? D2 : 0);
    float acc = 0.f;
    #pragma unroll 4
    for (int it = 0; it < 32; ++it){
      int n = it*64 + k8*8;
      short8 wv = *(const short8*)(wt + n);
      #pragma unroll
      for (int e = 0; e < 8; ++e)
        acc += bf2f((ushort_t)wv[e]) * bias[n+e];
    }
    acc += __shfl_down(acc, 4, 8);
    acc += __shfl_down(acc, 2, 8);
    acc += __shfl_down(acc, 1, 8);
    if (k8 == 0) (isU ? U : V)[(size_t)s*KDIM + j] = f2bf(acc);
  } else if (bid < 2080){
    int oi = (bid-2048)*32 + g;               // 0..1023
    int qi = oi >> 5, ki = oi & 31;
    const float* a = bias_all + (size_t)qi*N2;
    const float* bp = bias_all + (size_t)ki*N2 + D2;
    float acc = 0.f;
    #pragma unroll 4
    for (int it = 0; it < 64; ++it){
      int n = it*32 + k8*4;
      float4 av = *(const float4*)(a + n);
      float4 bv4 = *(const float4*)(bp + n);
      acc += av.x*bv4.x + av.y*bv4.y + av.z*bv4.z + av.w*bv4.w;
    }
    acc += __shfl_down(acc, 4, 8);
    acc += __shfl_down(acc, 2, 8);
    acc += __shfl_down(acc, 1, 8);
    if (k8 == 0) W4[oi] = acc;
  } else {
    int oi = (bid-2080)*32 + g;               // 0..1023
    int s = oi >> 5, qi = oi & 31;
    float acc = 0.f;
    const float* p = pe + (size_t)s*KDIM;
    const float* w = Wpv + (size_t)qi*D2 + 1024;
    #pragma unroll 4
    for (int it = 0; it < 32; ++it){
      int n = it*32 + k8*4;
      float4 av = *(const float4*)(p + n);
      float4 wv = *(const float4*)(w + n);
      acc += av.x*wv.x + av.y*wv.y + av.z*wv.z + av.w*wv.w;
    }
    const float* f = Wfc + (size_t)qi*D2;
    #pragma unroll 4
    for (int it = 0; it < 64; ++it){
      int n = it*32 + k8*4;
      float4 av = *(const float4*)(bv + n);
      float4 wv = *(const float4*)(f + n);
      acc += av.x*wv.x + av.y*wv.y + av.z*wv.z + av.w*wv.w;
    }
    acc += __shfl_down(acc, 4, 8);
    acc += __shfl_down(acc, 2, 8);
    acc += __shfl_down(acc, 1, 8);
    if (k8 == 0) biasp[oi] = acc;
  }
}

// ---------------- 256x256 8-phase GEMM (r7-verified body), templated ----------------
template<int NN, bool HASB>
__global__ __launch_bounds__(512, 1) void k_gemm(const ushort_t* __restrict__ xA,
                                                 const ushort_t* __restrict__ Bm,
                                                 const float* __restrict__ bias_all,
                                                 ushort_t* __restrict__ outm){
  __shared__ alignas(16) ushort_t sA[2][2*128*64];
  __shared__ alignas(16) ushort_t sB[2][2*128*64];

  const int t = threadIdx.x, w = t >> 6, l = t & 63;
  const int wr = w >> 2, wc = w & 3;
  const int lr = l & 15, lg = l >> 4;
  const int m0 = blockIdx.x * 256;
  const int n0 = blockIdx.y * 256;

  const ushort_t* gA = xA + (size_t)m0 * KDIM;
  const ushort_t* gB = Bm + (size_t)n0 * KDIM;

  floatx4 acc[8][4] = {};

  auto STAGE_A = [&](int kt, int d, int h){
    #pragma unroll
    for (int j = 0; j < 2; ++j){
      int p = j*512 + t;
      int wr_ = p >> 9, ridx = (p >> 3) & 63, c = (p & 7) ^ (ridx & 7);
      int R = wr_*128 + h*64 + ridx;
      gld16(gA + (size_t)R*KDIM + kt*64 + c*8, &sA[d][(size_t)h*8192 + (size_t)(j*512 + w*64)*8]);
    }
  };
  auto STAGE_B = [&](int kt, int d, int h){
    #pragma unroll
    for (int j = 0; j < 2; ++j){
      int p = j*512 + t;
      int wc_ = p >> 8, ridx = (p >> 3) & 31, c = (p & 7) ^ (ridx & 7);
      int R = wc_*64 + h*32 + ridx;
      gld16(gB + (size_t)R*KDIM + kt*64 + c*8, &sB[d][(size_t)h*8192 + (size_t)(j*512 + w*64)*8]);
    }
  };

  short8 a[8], b0[4], b1[4];
  auto RDA = [&](int d, int mh){
    #pragma unroll
    for (int mi = 0; mi < 4; ++mi)
      #pragma unroll
      for (int ks = 0; ks < 2; ++ks){
        int ch = (ks*4 + lg) ^ (lr & 7);
        a[mi*2+ks] = *(const short8*)&sA[d][(size_t)mh*8192 + (size_t)(wr*64 + mi*16 + lr)*64 + ch*8];
      }
  };
  auto RDB = [&](int d, int nh, short8* b){
    #pragma unroll
    for (int ni = 0; ni < 2; ++ni)
      #pragma unroll
      for (int ks = 0; ks < 2; ++ks){
        int ch = (ks*4 + lg) ^ (lr & 7);
        b[ni*2+ks] = *(const short8*)&sB[d][(size_t)nh*8192 + (size_t)(wc*32 + ni*16 + lr)*64 + ch*8];
      }
  };
  auto MM = [&](int mh, int nh, const short8* b){
    #pragma unroll
    for (int mi = 0; mi < 4; ++mi)
      #pragma unroll
      for (int ni = 0; ni < 2; ++ni)
        #pragma unroll
        for (int ks = 0; ks < 2; ++ks)
          acc[mh*4+mi][nh*2+ni] = __builtin_amdgcn_mfma_f32_16x16x32_bf16(
              a[mi*2+ks], b[ni*2+ks], acc[mh*4+mi][nh*2+ni], 0, 0, 0);
  };

  #define MIDBAR  do { barrier_raw(); WAIT_LGKM0; __builtin_amdgcn_sched_barrier(0); } while(0)
  #define PRIO_MM(mh, nh, b) do { __builtin_amdgcn_s_setprio(1); MM(mh, nh, b); __builtin_amdgcn_s_setprio(0); } while(0)

  STAGE_A(0,0,0); STAGE_B(0,0,1); STAGE_A(0,0,1); STAGE_B(0,0,0);
  STAGE_A(1,1,0); STAGE_B(1,1,1);
  WAIT_VM(4);
  barrier_raw();

  const int NI = KDIM / 128;
  for (int i = 0; i < NI; ++i){
    const int t1 = 2*i+1, t2 = 2*i+2, t3 = 2*i+3;
    const bool pre = (i < NI-1);

    RDA(0,0); RDB(0,0,b0);
    STAGE_A(t1,1,1); STAGE_B(t1,1,0);
    MIDBAR; PRIO_MM(0,0,b0);
    barrier_raw();
    RDB(0,1,b1);
    MIDBAR; PRIO_MM(0,1,b1);
    barrier_raw();
    RDA(0,1);
    if (pre) STAGE_A(t2,0,0);
    MIDBAR; PRIO_MM(1,1,b1);
    barrier_raw();
    if (pre) STAGE_B(t2,0,1);
    MIDBAR; PRIO_MM(1,0,b0);
    if (pre) { WAIT_VM(4); } else { WAIT_VM(0); }
    barrier_raw();

    RDA(1,0); RDB(1,0,b0);
    if (pre){ STAGE_A(t2,0,1); STAGE_B(t2,0,0); }
    MIDBAR; PRIO_MM(0,0,b0);
    barrier_raw();
    RDB(1,1,b1);
    MIDBAR; PRIO_MM(0,1,b1);
    barrier_raw();
    RDA(1,1);
    if (pre) STAGE_A(t3,1,0);
    MIDBAR; PRIO_MM(1,1,b1);
    barrier_raw();
    if (pre) STAGE_B(t3,1,1);
    MIDBAR; PRIO_MM(1,0,b0);
    if (pre) { WAIT_VM(4); }
    barrier_raw();
  }

  #pragma unroll
  for (int mh = 0; mh < 2; ++mh)
    #pragma unroll
    for (int mi = 0; mi < 4; ++mi)
      #pragma unroll
      for (int nh = 0; nh < 2; ++nh)
        #pragma unroll
        for (int ni = 0; ni < 2; ++ni)
          #pragma unroll
          for (int r = 0; r < 4; ++r){
            int row = m0 + wr*128 + mh*64 + mi*16 + lg*4 + r;
            int col = n0 + wc*64 + nh*32 + ni*16 + lr;
            float v = acc[mh*4+mi][nh*2+ni][r];
            if constexpr (HASB) v += bias_all[(size_t)(row & 31)*NN + col];
            outm[(size_t)row*NN + col] = f2bf(v);
          }
  #undef MIDBAR
  #undef PRIO_MM
}

// ---------------- per-batch tail: 4 small MFMA GEMMs + softmax + weighted sum ----------------
__global__ __launch_bounds__(256) void k_fuse2(
    const ushort_t* __restrict__ xb, const ushort_t* __restrict__ Yb,
    const ushort_t* __restrict__ U, const ushort_t* __restrict__ V,
    const ushort_t* __restrict__ Wpvb, const float* __restrict__ W4,
    const float* __restrict__ biasp, const float* __restrict__ bfc,
    float* __restrict__ out){
  __shared__ float p1[4*1024];
  __shared__ float p3[4*1024];
  __shared__ float pp[4*1024];
  __shared__ float red[4];
  const int b = blockIdx.x;
  const int t = threadIdx.x, w = t >> 6, l = t & 63;
  const int lr = l & 15, lg = l >> 4;
  const int jb = w*256;   // wave's K-slice

  const ushort_t* gx = xb + (size_t)b*32*KDIM;
  const ushort_t* gy = Yb + (size_t)b*32*KDIM;

  short8 xf[2][8], ya[2][8], bo[2][8];
  #pragma unroll
  for (int rf = 0; rf < 2; ++rf)
    #pragma unroll
    for (int ks = 0; ks < 8; ++ks){
      size_t o = (size_t)(rf*16+lr)*KDIM + jb + ks*32 + lg*8;
      xf[rf][ks] = *(const short8*)(gx + o);
      ya[rf][ks] = *(const short8*)(gy + o);
    }
  #pragma unroll
  for (int bf = 0; bf < 2; ++bf)
    #pragma unroll
    for (int ks = 0; ks < 8; ++ks)
      bo[bf][ks] = *(const short8*)(U + (size_t)(bf*16+lr)*KDIM + jb + ks*32 + lg*8);

  floatx4 aL[2][2] = {}, a3[2][2] = {}, aP[2][2] = {};
  #pragma unroll
  for (int rf = 0; rf < 2; ++rf)
    #pragma unroll
    for (int bf = 0; bf < 2; ++bf)
      #pragma unroll
      for (int ks = 0; ks < 8; ++ks){
        aL[rf][bf] = __builtin_amdgcn_mfma_f32_16x16x32_bf16(ya[rf][ks], xf[bf][ks], aL[rf][bf], 0, 0, 0);
        aL[rf][bf] = __builtin_amdgcn_mfma_f32_16x16x32_bf16(xf[rf][ks], bo[bf][ks], aL[rf][bf], 0, 0, 0);
      }
  #pragma unroll
  for (int bf = 0; bf < 2; ++bf)
    #pragma unroll
    for (int ks = 0; ks < 8; ++ks)
      bo[bf][ks] = *(const short8*)(V + (size_t)(bf*16+lr)*KDIM + jb + ks*32 + lg*8);
  #pragma unroll
  for (int rf = 0; rf < 2; ++rf)
    #pragma unroll
    for (int bf = 0; bf < 2; ++bf)
      #pragma unroll
      for (int ks = 0; ks < 8; ++ks)
        a3[rf][bf] = __builtin_amdgcn_mfma_f32_16x16x32_bf16(xf[rf][ks], bo[bf][ks], a3[rf][bf], 0, 0, 0);
  #pragma unroll
  for (int bf = 0; bf < 2; ++bf)
    #pragma unroll
    for (int ks = 0; ks < 8; ++ks)
      bo[bf][ks] = *(const short8*)(Wpvb + (size_t)(bf*16+lr)*KDIM + jb + ks*32 + lg*8);
  #pragma unroll
  for (int rf = 0; rf < 2; ++rf)
    #pragma unroll
    for (int bf = 0; bf < 2; ++bf)
      #pragma unroll
      for (int ks = 0; ks < 8; ++ks)
        aP[rf][bf] = __builtin_amdgcn_mfma_f32_16x16x32_bf16(xf[rf][ks], bo[bf][ks], aP[rf][bf], 0, 0, 0);

  #pragma unroll
  for (int rf = 0; rf < 2; ++rf)
    #pragma unroll
    for (int bf = 0; bf < 2; ++bf)
      #pragma unroll
      for (int r = 0; r < 4; ++r){
        int row = rf*16 + lg*4 + r, col = bf*16 + lr;
        p1[w*1024 + row*32 + col] = aL[rf][bf][r];
        p3[w*1024 + row*32 + col] = a3[rf][bf][r];
        pp[w*1024 + row*32 + col] = aP[rf][bf][r];
      }
  __syncthreads();
  #pragma unroll
  for (int h = 0; h < 4; ++h){
    int idx = h*256 + t;
    float s1 = p1[idx] + p1[1024+idx] + p1[2048+idx] + p1[3072+idx];
    float s3 = p3[idx] + p3[1024+idx] + p3[2048+idx] + p3[3072+idx];
    float sp = pp[idx] + pp[1024+idx] + pp[2048+idx] + pp[3072+idx];
    p1[idx] = s1; p3[idx] = s3; pp[idx] = sp;
  }
  __syncthreads();
  if (t < 32){
    int ki = t;
    float lgv[32];
    float mx = -1e30f;
    #pragma unroll
    for (int qi = 0; qi < 32; ++qi){
      float v = (p1[qi*32+ki] + p3[ki*32+qi] + W4[qi*32+ki]) * 0.022097086912079608f;
      lgv[qi] = v; mx = fmaxf(mx, v);
    }
    float sm = 0.f;
    #pragma unroll
    for (int qi = 0; qi < 32; ++qi){ float e = __expf(lgv[qi]-mx); lgv[qi] = e; sm += e; }
    float inv = 1.f/sm;
    #pragma unroll
    for (int qi = 0; qi < 32; ++qi) p1[qi*32+ki] = lgv[qi]*inv;
  }
  __syncthreads();
  float sum = 0.f;
  #pragma unroll
  for (int h = 0; h < 4; ++h){
    int idx = h*256 + t;
    int qi = idx >> 5, ki = idx & 31;
    sum += p1[qi*32+ki] * (pp[ki*32+qi] + biasp[ki*32+qi]);
  }
  #pragma unroll
  for (int off = 32; off > 0; off >>= 1) sum += __shfl_down(sum, off, 64);
  if (l == 0) red[w] = sum;
  __syncthreads();
  if (t == 0) out[b] = red[0] + red[1] + red[2] + red[3] + bfc[0];
}

// ---------------- host ----------------
extern "C" void kernel_launch(void* const* d_in, const int* in_sizes, int n_in,
                              void* d_out, int out_size, void* d_ws, size_t ws_size,
                              hipStream_t stream) {
  const float* x   = (const float*)d_in[0];
  const float* pe  = (const float*)d_in[1];
  const float* Wq  = (const float*)d_in[2];
  const float* bq  = (const float*)d_in[3];
  const float* Wk  = (const float*)d_in[4];
  const float* bk  = (const float*)d_in[5];
  const float* Wv  = (const float*)d_in[6];
  const float* bv  = (const float*)d_in[7];
  const float* Wfc = (const float*)d_in[8];
  const float* bfc = (const float*)d_in[9];
  float* out = (float*)d_out;
  (void)in_sizes; (void)n_in; (void)out_size; (void)ws_size;

  char* ws = (char*)d_ws;
  size_t off = 0;
  auto alloc = [&](size_t bytes) -> void* {
    void* p = ws + off;
    off += (bytes + 255) & ~(size_t)255;
    return p;
  };
  ushort_t* xb       = (ushort_t*)alloc((size_t)M_TOT * KDIM * 2);   //  64 MiB
  ushort_t* Y        = (ushort_t*)alloc((size_t)M_TOT * KDIM * 2);   //  64 MiB
  ushort_t* WqT      = (ushort_t*)alloc((size_t)KDIM * D2 * 2);      //   4 MiB
  ushort_t* WkT      = (ushort_t*)alloc((size_t)KDIM * D2 * 2);      //   4 MiB
  float*    Mpart    = (float*)   alloc((size_t)8 * KDIM * KDIM * 4);// 32 MiB
  ushort_t* Mt       = (ushort_t*)alloc((size_t)KDIM * KDIM * 2);    //   2 MiB
  float*    wpv_part = (float*)   alloc((size_t)16 * 32 * D2 * 4);   //   4 MiB
  float*    Wpv      = (float*)   alloc((size_t)32 * D2 * 4);        // 256 KiB
  ushort_t* Wpvb     = (ushort_t*)alloc((size_t)32 * KDIM * 2);      //  64 KiB
  float*    bias_all = (float*)   alloc((size_t)32 * N2 * 4);        // 512 KiB
  ushort_t* U        = (ushort_t*)alloc((size_t)32 * KDIM * 2);      //  64 KiB
  ushort_t* V        = (ushort_t*)alloc((size_t)32 * KDIM * 2);      //  64 KiB
  float*    W4       = (float*)   alloc((size_t)32 * 32 * 4);        //   4 KiB
  float*    biasp    = (float*)   alloc((size_t)32 * 32 * 4);        //   4 KiB

  k_cast_x <<<dim3(16384),      dim3(256), 0, stream>>>(x, xb);
  k_trans  <<<dim3(16, 32, 2),  dim3(256), 0, stream>>>(Wq, Wk, WqT, WkT);
  k_bias   <<<dim3(512),        dim3(256), 0, stream>>>(pe, Wq, bq, Wk, bk, bias_all);
  k_mt     <<<dim3(8, 8, 8),    dim3(256), 0, stream>>>(WkT, WqT, Mpart);
  k_wpv1   <<<dim3(32, 16),     dim3(256), 0, stream>>>(Wv, Wfc, wpv_part);
  k_red    <<<dim3(768),        dim3(256), 0, stream>>>(Mpart, Mt, wpv_part, Wpv, Wpvb);
  k_tab    <<<dim3(2112),       dim3(256), 0, stream>>>(WqT, WkT, bias_all, pe, Wpv, bv, Wfc, U, V, W4, biasp);
  k_gemm<1024,false><<<dim3(M_TOT/256, 4), dim3(512), 0, stream>>>(xb, Mt, nullptr, Y);
  k_fuse2  <<<dim3(NB),         dim3(256), 0, stream>>>(xb, Y, U, V, Wpvb, W4, biasp, bfc, out);
}